// Round 13
// baseline (143.631 us; speedup 1.0000x reference)
//
#include <hip/hip_runtime.h>
#include <hip/hip_bf16.h>

typedef __attribute__((ext_vector_type(8))) __bf16 bf16x8;
typedef __attribute__((ext_vector_type(4))) float f32x4;
typedef __attribute__((ext_vector_type(4))) int int4v;

#define NB 8
#define NN 2048
#define ND 256
#define L2E 1.44269504f
#define AS1 __attribute__((address_space(1)))
#define AS3 __attribute__((address_space(3)))

// ---------------------------------------------------------------------------
// KPREP: grid-partitioned fusion (one dispatch, independent roles):
//   [0,512):        k1 role - hT2[b][jc][d][32] bf16 via MFMA
//   [512,768):      k2 role - elc/erx score tables
//   [768,4864):     pack role - adj -> bitmask, ILP style (8 int4 in flight
//                   per thread, no ballot chain -> occupancy-tolerant)
// adj's 134 MB HBM stream runs concurrently with k1's MFMA.
// ---------------------------------------------------------------------------
__global__ __launch_bounds__(256) void kprep(
    const float* __restrict__ x, const float* __restrict__ W,
    const float* __restrict__ a, const int* __restrict__ adj,
    __bf16* __restrict__ hT2, float* __restrict__ elc,
    float* __restrict__ erx, unsigned* __restrict__ mask32) {
  __shared__ __bf16 hlds[256 * 34];
  __shared__ float wls[ND], wrs[ND];
  int blk = blockIdx.x;
  int tid = threadIdx.x;

  if (blk >= 768) {
    // ---- pack role: 1 word (32 adj ints) per thread ----
    long g = (long)(blk - 768) * 256 + tid;  // < 1048576
    const int4v* ap = (const int4v*)(adj + g * 32);
    int4v v0 = ap[0], v1 = ap[1], v2 = ap[2], v3 = ap[3];
    int4v v4 = ap[4], v5 = ap[5], v6 = ap[6], v7 = ap[7];
    unsigned m = 0;
#define PK(VV, BASE)                                                   \
    _Pragma("unroll") for (int k = 0; k < 4; ++k)                      \
        m |= (VV[k] != 0 ? 1u : 0u) << ((BASE) + k);
    PK(v0, 0) PK(v1, 4) PK(v2, 8) PK(v3, 12)
    PK(v4, 16) PK(v5, 20) PK(v6, 24) PK(v7, 28)
#undef PK
    mask32[g] = m;
    return;
  }

  if (blk >= 512) {
    // ---- k2 role ----
    int t = tid;
    {
      float swl = 0.f, swr = 0.f;
#pragma unroll 8
      for (int o = 0; o < ND; ++o) {
        float wv = W[(long)o * ND + t];
        swl = fmaf(a[o], wv, swl);
        swr = fmaf(a[ND + o], wv, swr);
      }
      wls[t] = swl;
      wrs[t] = swr;
    }
    __syncthreads();
    int r = t >> 2, q = t & 3;
    long row = (long)(blk - 512) * 64 + r;
    const f32x4* xr = (const f32x4*)(x + row * ND);
    float sl = 0.f, sr = 0.f;
#pragma unroll
    for (int ii = 0; ii < 16; ++ii) {
      int idx = q + (ii << 2);
      f32x4 xv = xr[idx];
      f32x4 lv = *(const f32x4*)(wls + idx * 4);
      f32x4 rv = *(const f32x4*)(wrs + idx * 4);
      sl += xv[0] * lv[0] + xv[1] * lv[1] + xv[2] * lv[2] + xv[3] * lv[3];
      sr += xv[0] * rv[0] + xv[1] * rv[1] + xv[2] * rv[2] + xv[3] * rv[3];
    }
    sl += __shfl_xor(sl, 1);
    sl += __shfl_xor(sl, 2);
    sr += __shfl_xor(sr, 1);
    sr += __shfl_xor(sr, 2);
    if (q == 0) {
      elc[row] = (-0.8f * sl - 16.0f) * L2E;
      erx[row] = (sr - 16.0f) * L2E;
    }
    return;
  }

  // ---- k1 role: h = x @ W^T, store hT2 chunk-contiguous ----
  int wid = tid >> 6, lane = tid & 63;
  int msub = wid & 1, nh = wid >> 1;
  int lrow = lane & 15, kg = lane >> 4;
  int m0 = blk * 32;
  int row = m0 + msub * 16 + lrow;

  f32x4 acc[8];
#pragma unroll
  for (int f = 0; f < 8; ++f) acc[f] = (f32x4){0.f, 0.f, 0.f, 0.f};

#pragma unroll
  for (int k0 = 0; k0 < ND; k0 += 32) {
    int kk = k0 + kg * 8;
    const f32x4* xa = (const f32x4*)(x + (long)row * ND + kk);
    f32x4 a0 = xa[0], a1 = xa[1];
    bf16x8 afrag;
    afrag[0] = (__bf16)a0[0]; afrag[1] = (__bf16)a0[1];
    afrag[2] = (__bf16)a0[2]; afrag[3] = (__bf16)a0[3];
    afrag[4] = (__bf16)a1[0]; afrag[5] = (__bf16)a1[1];
    afrag[6] = (__bf16)a1[2]; afrag[7] = (__bf16)a1[3];
#pragma unroll
    for (int f = 0; f < 8; ++f) {
      int o = nh * 128 + f * 16 + lrow;
      const f32x4* wb = (const f32x4*)(W + (long)o * ND + kk);
      f32x4 b0 = wb[0], b1 = wb[1];
      bf16x8 bfrag;
      bfrag[0] = (__bf16)b0[0]; bfrag[1] = (__bf16)b0[1];
      bfrag[2] = (__bf16)b0[2]; bfrag[3] = (__bf16)b0[3];
      bfrag[4] = (__bf16)b1[0]; bfrag[5] = (__bf16)b1[1];
      bfrag[6] = (__bf16)b1[2]; bfrag[7] = (__bf16)b1[3];
      acc[f] = __builtin_amdgcn_mfma_f32_16x16x32_bf16(afrag, bfrag, acc[f], 0, 0, 0);
    }
  }

#pragma unroll
  for (int f = 0; f < 8; ++f) {
    int d = nh * 128 + f * 16 + lrow;
#pragma unroll
    for (int r = 0; r < 4; ++r) {
      int nloc = msub * 16 + kg * 4 + r;
      hlds[d * 34 + nloc] = (__bf16)acc[f][r];
    }
  }
  __syncthreads();
  {
    int b = m0 >> 11;
    int jc = (m0 & (NN - 1)) >> 5;
    const int* src = (const int*)(hlds + tid * 34);
    int tmp[16];
#pragma unroll
    for (int j = 0; j < 16; ++j) tmp[j] = src[j];
    __bf16* dst = hT2 + (((long)b * 64 + jc) * 256 + tid) * 32;
#pragma unroll
    for (int j = 0; j < 4; ++j)
      *(int4v*)(dst + j * 8) = *(int4v*)(tmp + j * 4);
  }
}

// ---------------------------------------------------------------------------
// K3: fused mask + softmax + PV, register-direct B-frags (no hbuf, no main-
// loop barriers). 1024 blocks (b=blk&7 XCD pin, it=blk>>3: 16-row i-tile) x
// 256 thr (4 waves = 64-d quarters). B-frag = 1 KB coalesced L2-hot load
// (chunk-contiguous hT2); 3 static register sets, 2-chunk prefetch distance,
// unroll-x3 rotation. LDS: mask tile 4 KB XOR-flat + erx 8 KB, staged once.
// p = bit ? exp2(max(x16, 0.2*x16 + 3.2*L2E + elc_i)) : 0.
// 4 blocks/CU (launch_bounds caps VGPR at 128).
// ---------------------------------------------------------------------------
__global__ __launch_bounds__(256, 4) void k3_main(
    const unsigned* __restrict__ mask32, const __bf16* __restrict__ hT2,
    const float* __restrict__ elc, const float* __restrict__ erx,
    float* __restrict__ out) {
  __shared__ float er_lds[NN];         // 8 KB
  __shared__ unsigned mask_lds[1024];  // 4 KB flat [R*64 + (w ^ (R&15))]

  int blk = blockIdx.x;
  int b = blk & 7;    // batch -> XCD pin
  int it = blk >> 3;  // i-tile 0..127 (16 rows)
  int tid = threadIdx.x;
  int wid = tid >> 6, lane = tid & 63;  // wid = 64-d quarter
  int lrow = lane & 15, kg = lane >> 4, kg8 = kg * 8;
  int irow = it * 16 + lrow;

  const __bf16* hT2b = hT2 + (long)b * 64 * 8192;
  const unsigned* maskb = mask32 + ((long)b * NN + (long)it * 16) * 64;
  const float* erxb = erx + (long)b * NN;
  float c1s = elc[b * NN + irow];

  // ---- prologue: er -> LDS, mask tile -> XOR-flat LDS, one barrier ----
  __builtin_amdgcn_global_load_lds((const AS1 void*)(erxb + tid * 4),
                                   (AS3 void*)(er_lds + tid * 4), 16, 0, 0);
  __builtin_amdgcn_global_load_lds((const AS1 void*)(erxb + 1024 + tid * 4),
                                   (AS3 void*)(er_lds + 1024 + tid * 4), 16, 0, 0);
  int4v mw = *(const int4v*)(maskb + tid * 4);
  asm volatile("s_waitcnt vmcnt(0)" ::: "memory");
  {
    int R = tid >> 4;
    int w0 = (tid & 15) * 4;
#pragma unroll
    for (int i = 0; i < 4; ++i)
      mask_lds[R * 64 + ((w0 + i) ^ (R & 15))] = (unsigned)mw[i];
  }
  asm volatile("s_waitcnt lgkmcnt(0)" ::: "memory");
  __builtin_amdgcn_s_barrier();

  // B-frag base: lane reads hT2[chunk][d = wid*64 + f*16 + lrow][kg*8..+7]
  const __bf16* bbase = hT2b + (long)(wid * 64 + lrow) * 32 + kg8;
  int mbase = lrow * 64;
  int mxor = lrow & 15;

  f32x4 acc[4];
#pragma unroll
  for (int f = 0; f < 4; ++f) acc[f] = (f32x4){0.f, 0.f, 0.f, 0.f};
  float den = 0.f;

  bf16x8 b0_0, b1_0, b2_0, b3_0;
  bf16x8 b0_1, b1_1, b2_1, b3_1;
  bf16x8 b0_2, b1_2, b2_2, b3_2;

#define LOADB(S, TCV)                                                       \
  {                                                                         \
    const __bf16* p_ = bbase + (long)(TCV)*8192;                            \
    b0_##S = *(const bf16x8*)(p_);                                          \
    b1_##S = *(const bf16x8*)(p_ + 512);                                    \
    b2_##S = *(const bf16x8*)(p_ + 1024);                                   \
    b3_##S = *(const bf16x8*)(p_ + 1536);                                   \
  }

#define COMP(S, TCV)                                                        \
  {                                                                         \
    unsigned msh = mask_lds[mbase + ((TCV) ^ mxor)] >> kg8;                 \
    const float* ep_ = er_lds + (TCV)*32 + kg8;                             \
    f32x4 xa_ = *(const f32x4*)ep_;                                         \
    f32x4 xb_ = *(const f32x4*)(ep_ + 4);                                   \
    bf16x8 pfrag;                                                           \
    float ps = 0.f;                                                         \
    _Pragma("unroll") for (int e = 0; e < 8; ++e) {                         \
      float x16 = (e < 4) ? xa_[e] : xb_[e - 4];                            \
      float x02 = fmaf(0.2f, x16, 4.61662413f);                             \
      float m_ = fmaxf(x16, x02 + c1s);                                     \
      float p = __builtin_amdgcn_exp2f(m_);                                 \
      p = ((msh >> e) & 1u) ? p : 0.0f;                                     \
      ps += p;                                                              \
      pfrag[e] = (__bf16)p;                                                 \
    }                                                                       \
    den += ps;                                                              \
    __builtin_amdgcn_s_setprio(1);                                          \
    acc[0] = __builtin_amdgcn_mfma_f32_16x16x32_bf16(pfrag, b0_##S, acc[0], 0, 0, 0); \
    acc[1] = __builtin_amdgcn_mfma_f32_16x16x32_bf16(pfrag, b1_##S, acc[1], 0, 0, 0); \
    acc[2] = __builtin_amdgcn_mfma_f32_16x16x32_bf16(pfrag, b2_##S, acc[2], 0, 0, 0); \
    acc[3] = __builtin_amdgcn_mfma_f32_16x16x32_bf16(pfrag, b3_##S, acc[3], 0, 0, 0); \
    __builtin_amdgcn_s_setprio(0);                                          \
  }

  // prologue: sets 0,1 hold chunks 0,1
  LOADB(0, 0);
  LOADB(1, 1);
  // main: T = 0..19 computes chunks 3T..3T+2, loads 3T+2..3T+4 (max 63)
  for (int T = 0; T < 20; ++T) {
    int tc = T * 3;
    LOADB(2, tc + 2);
    COMP(0, tc);
    LOADB(0, tc + 3);
    COMP(1, tc + 1);
    LOADB(1, tc + 4);
    COMP(2, tc + 2);
  }
  // epilogue: chunks 60..63 (after loop: set0=60, set1=61)
  LOADB(2, 62);
  COMP(0, 60);
  LOADB(0, 63);
  COMP(1, 61);
  COMP(2, 62);
  COMP(0, 63);

#undef LOADB
#undef COMP

  // den: reduce across the 4 k-groups (lanes sharing lrow)
  den += __shfl_xor(den, 16);
  den += __shfl_xor(den, 32);
  float rdiv[4];
#pragma unroll
  for (int r = 0; r < 4; ++r) rdiv[r] = 1.0f / __shfl(den, kg * 4 + r);

  float* outb = out + ((long)b * NN + (long)it * 16) * ND;
#pragma unroll
  for (int f = 0; f < 4; ++f) {
    int dcol = wid * 64 + f * 16 + lrow;
#pragma unroll
    for (int r = 0; r < 4; ++r)
      outb[(long)(kg * 4 + r) * ND + dcol] = acc[f][r] * rdiv[r];
  }
}

// ---------------------------------------------------------------------------
extern "C" void kernel_launch(void* const* d_in, const int* in_sizes, int n_in,
                              void* d_out, int out_size, void* d_ws,
                              size_t ws_size, hipStream_t stream) {
  const float* x = (const float*)d_in[0];
  const int* adj = (const int*)d_in[1];
  const float* W = (const float*)d_in[2];
  const float* a = (const float*)d_in[3];
  float* out = (float*)d_out;

  char* ws = (char*)d_ws;
  const size_t base = 8u * 1024u * 1024u;
  __bf16* hT2 = (__bf16*)ws;                          // 8 MB
  float* elc = (float*)(ws + base);                   // 64 KB
  float* erx = (float*)(ws + base + 65536u);          // 64 KB
  unsigned* mask = (unsigned*)(ws + base + 131072u);  // 4 MB

  kprep<<<dim3(4864), dim3(256), 0, stream>>>(x, W, a, adj, hT2, elc, erx,
                                              mask);
  k3_main<<<dim3(1024), dim3(256), 0, stream>>>(mask, hT2, elc, erx, out);
}